// Round 3
// baseline (172.706 us; speedup 1.0000x reference)
//
#include <hip/hip_runtime.h>
#include <hip/hip_bf16.h>

#define SS 2048
#define DD 128
#define BB 16
#define LDST 136  // 128 + 8 ushort pad for conflict-free b128 frag reads

typedef short bf16x8 __attribute__((ext_vector_type(8)));
typedef float f32x4 __attribute__((ext_vector_type(4)));
typedef unsigned short ushort_t;

__device__ __forceinline__ unsigned short f2bf(float f) {
  union { float f; unsigned u; } v; v.f = f;
  unsigned r = v.u + 0x7fffu + ((v.u >> 16) & 1u);  // RNE
  return (unsigned short)(r >> 16);
}
__device__ __forceinline__ float fexp2(float x) { return __builtin_amdgcn_exp2f(x); }

// ---------------------------------------------------------------------------
// wprep: wt_g = [Wq^T * log2e/sqrt(U) ; Wk^T] bf16 [256][128]. grid 128.
// ---------------------------------------------------------------------------
__global__ __launch_bounds__(256) void wprep(
    const float* __restrict__ Wq, const float* __restrict__ Wk,
    ushort_t* __restrict__ wt_g) {
  int idx = blockIdx.x * 256 + threadIdx.x;  // 0..32767
  int r = idx & 16383, uu = r >> 7, d = r & 127;
  if (idx < 16384)
    wt_g[uu * 128 + d] = f2bf(Wq[d * 128 + uu] * 0.1275174346f);  // log2e/sqrt(128)
  else
    wt_g[(uu + 128) * 128 + d] = f2bf(Wk[d * 128 + uu]);
}

// ---------------------------------------------------------------------------
// qk_gemm: [qb|kb] = bf16(x) @ wt_g^T. grid 512 (64 rows/block), block 256.
// x read fp32 coalesced -> LDS bf16; W frags register-resident per wave
// (wave w owns output cols [w*64, +64)); C repacked via LDS, uint4 stores.
// ---------------------------------------------------------------------------
__global__ __launch_bounds__(256, 2) void qk_gemm(
    const float* __restrict__ x, const ushort_t* __restrict__ wt_g,
    ushort_t* __restrict__ qb, ushort_t* __restrict__ kb) {
  __shared__ ushort_t xs[64 * LDST];
  __shared__ ushort_t sc[64 * 264];
  const int tid = threadIdx.x, wave = tid >> 6, lane = tid & 63;
  const int lq = lane & 15, quad = lane >> 4;
  const int m0 = blockIdx.x * 64;

#pragma unroll
  for (int i = 0; i < 8; ++i) {  // stage x: 64x128 fp32 -> bf16
    int idx = i * 256 + tid;
    int row = idx >> 5, c4 = (idx & 31) * 4;
    const float4 v = *(const float4*)(x + (size_t)(m0 + row) * DD + c4);
    ushort4 h;
    h.x = f2bf(v.x); h.y = f2bf(v.y); h.z = f2bf(v.z); h.w = f2bf(v.w);
    *(ushort4*)(&xs[row * LDST + c4]) = h;
  }
  bf16x8 wf[4][4];  // wave's 64 output cols, K=128
#pragma unroll
  for (int nt = 0; nt < 4; ++nt)
#pragma unroll
    for (int ks = 0; ks < 4; ++ks)
      wf[nt][ks] = *(const bf16x8*)(wt_g + (wave * 64 + nt * 16 + lq) * 128 + ks * 32 + quad * 8);
  __syncthreads();

  f32x4 acc[4][4];
#pragma unroll
  for (int mt = 0; mt < 4; ++mt)
#pragma unroll
    for (int nt = 0; nt < 4; ++nt) acc[mt][nt] = (f32x4){0.f, 0.f, 0.f, 0.f};
#pragma unroll
  for (int mt = 0; mt < 4; ++mt) {
    bf16x8 af[4];
#pragma unroll
    for (int ks = 0; ks < 4; ++ks)
      af[ks] = *(const bf16x8*)(&xs[(mt * 16 + lq) * LDST + ks * 32 + quad * 8]);
#pragma unroll
    for (int nt = 0; nt < 4; ++nt)
#pragma unroll
      for (int ks = 0; ks < 4; ++ks)
        acc[mt][nt] = __builtin_amdgcn_mfma_f32_16x16x32_bf16(af[ks], wf[nt][ks], acc[mt][nt], 0, 0, 0);
  }
#pragma unroll
  for (int mt = 0; mt < 4; ++mt)
#pragma unroll
    for (int nt = 0; nt < 4; ++nt)
#pragma unroll
      for (int r = 0; r < 4; ++r)
        sc[(mt * 16 + quad * 4 + r) * 264 + wave * 64 + nt * 16 + lq] = f2bf(acc[mt][nt][r]);
  __syncthreads();
#pragma unroll
  for (int i = 0; i < 8; ++i) {  // coalesced uint4 stores
    int idx = i * 256 + tid;
    int row = idx >> 5, col = (idx & 31) * 8;
    uint4 vv = *(const uint4*)(&sc[row * 264 + col]);
    if (col < 128) *(uint4*)(qb + (size_t)(m0 + row) * DD + col) = vv;
    else           *(uint4*)(kb + (size_t)(m0 + row) * DD + (col - 128)) = vv;
  }
}

// ---------------------------------------------------------------------------
// rowsum: l[b,i] += sum_j exp2(s2_ij) over this block's 512-col j-chunk.
// grid 2048 = jc(4) x b(16) x ib(32); block 256; 34KB LDS -> 4 blocks/CU.
// ---------------------------------------------------------------------------
__global__ __launch_bounds__(256, 4) void rowsum(
    const ushort_t* __restrict__ qb, const ushort_t* __restrict__ kb,
    float* __restrict__ l) {
  __shared__ ushort_t kt[128 * LDST];
  const int blk = blockIdx.x;
  const int jc = blk >> 9, b = (blk >> 5) & 15, ib = blk & 31;
  const int i0 = ib * 64, j0 = jc * 512;
  const int tid = threadIdx.x, wave = tid >> 6, lane = tid & 63;
  const int lq = lane & 15, quad = lane >> 4;

  bf16x8 af[4][4];
  const ushort_t* qbase = qb + (size_t)(b * SS + i0 + lq) * DD + quad * 8;
#pragma unroll
  for (int mt = 0; mt < 4; ++mt)
#pragma unroll
    for (int ks = 0; ks < 4; ++ks)
      af[mt][ks] = *(const bf16x8*)(qbase + mt * 16 * DD + ks * 32);

  float rs[4][4];
#pragma unroll
  for (int mt = 0; mt < 4; ++mt)
#pragma unroll
    for (int r = 0; r < 4; ++r) rs[mt][r] = 0.f;

  for (int jt = 0; jt < 4; ++jt) {
    __syncthreads();
#pragma unroll
    for (int i = 0; i < 8; ++i) {
      int idx = i * 256 + tid, row = idx >> 4, cb = (idx & 15) * 8;
      *(uint4*)(&kt[row * LDST + cb]) =
          *(const uint4*)(kb + (size_t)(b * SS + j0 + jt * 128 + row) * DD + cb);
    }
    __syncthreads();
#pragma unroll
    for (int nt = 0; nt < 2; ++nt) {
      f32x4 acc[4];
#pragma unroll
      for (int mt = 0; mt < 4; ++mt) acc[mt] = (f32x4){0.f, 0.f, 0.f, 0.f};
#pragma unroll
      for (int ks = 0; ks < 4; ++ks) {
        bf16x8 bfr = *(const bf16x8*)(&kt[(wave * 32 + nt * 16 + lq) * LDST + ks * 32 + quad * 8]);
#pragma unroll
        for (int mt = 0; mt < 4; ++mt)
          acc[mt] = __builtin_amdgcn_mfma_f32_16x16x32_bf16(af[mt][ks], bfr, acc[mt], 0, 0, 0);
      }
#pragma unroll
      for (int mt = 0; mt < 4; ++mt)
#pragma unroll
        for (int r = 0; r < 4; ++r) rs[mt][r] += fexp2(acc[mt][r]);
    }
  }
#pragma unroll
  for (int d2 = 1; d2 <= 8; d2 <<= 1)
#pragma unroll
    for (int mt = 0; mt < 4; ++mt)
#pragma unroll
      for (int r = 0; r < 4; ++r) rs[mt][r] += __shfl_xor(rs[mt][r], d2, 64);
  if (lq == 0) {
#pragma unroll
    for (int mt = 0; mt < 4; ++mt)
#pragma unroll
      for (int r = 0; r < 4; ++r)
        atomicAdd(&l[b * SS + i0 + mt * 16 + quad * 4 + r], rs[mt][r]);
  }
}

// ---------------------------------------------------------------------------
// cvec: c[b,i] = sigmoid(theta_i - mu_i * t[b,i]) / l[b,i].  grid 128.
// ---------------------------------------------------------------------------
__global__ __launch_bounds__(256) void cvec(
    const float* __restrict__ t, const float* __restrict__ theta,
    const float* __restrict__ mu, const float* __restrict__ l,
    float* __restrict__ c) {
  int idx = blockIdx.x * 256 + threadIdx.x;  // 32768
  int i = idx & 2047;
  float z = theta[i] - mu[i] * t[idx];
  float tf = 1.f / (1.f + fexp2(-z * 1.44269504f));
  c[idx] = tf / l[idx];
}

// ---------------------------------------------------------------------------
// colsum: w[b,j] += sum_i c_i * exp2(s2_ij) over this block's 64 i-rows.
// Same grid/LDS/occupancy as rowsum.
// ---------------------------------------------------------------------------
__global__ __launch_bounds__(256, 4) void colsum(
    const ushort_t* __restrict__ qb, const ushort_t* __restrict__ kb,
    const float* __restrict__ c, float* __restrict__ w) {
  __shared__ ushort_t kt[128 * LDST];
  const int blk = blockIdx.x;
  const int jc = blk >> 9, b = (blk >> 5) & 15, ib = blk & 31;
  const int i0 = ib * 64, j0 = jc * 512;
  const int tid = threadIdx.x, wave = tid >> 6, lane = tid & 63;
  const int lq = lane & 15, quad = lane >> 4;

  bf16x8 af[4][4];
  const ushort_t* qbase = qb + (size_t)(b * SS + i0 + lq) * DD + quad * 8;
#pragma unroll
  for (int mt = 0; mt < 4; ++mt)
#pragma unroll
    for (int ks = 0; ks < 4; ++ks)
      af[mt][ks] = *(const bf16x8*)(qbase + mt * 16 * DD + ks * 32);

  float creg[4][4];
#pragma unroll
  for (int mt = 0; mt < 4; ++mt)
#pragma unroll
    for (int r = 0; r < 4; ++r)
      creg[mt][r] = c[b * SS + i0 + mt * 16 + quad * 4 + r];

  for (int jt = 0; jt < 4; ++jt) {
    __syncthreads();
#pragma unroll
    for (int i = 0; i < 8; ++i) {
      int idx = i * 256 + tid, row = idx >> 4, cb = (idx & 15) * 8;
      *(uint4*)(&kt[row * LDST + cb]) =
          *(const uint4*)(kb + (size_t)(b * SS + j0 + jt * 128 + row) * DD + cb);
    }
    __syncthreads();
#pragma unroll
    for (int nt = 0; nt < 2; ++nt) {
      f32x4 acc[4];
#pragma unroll
      for (int mt = 0; mt < 4; ++mt) acc[mt] = (f32x4){0.f, 0.f, 0.f, 0.f};
#pragma unroll
      for (int ks = 0; ks < 4; ++ks) {
        bf16x8 bfr = *(const bf16x8*)(&kt[(wave * 32 + nt * 16 + lq) * LDST + ks * 32 + quad * 8]);
#pragma unroll
        for (int mt = 0; mt < 4; ++mt)
          acc[mt] = __builtin_amdgcn_mfma_f32_16x16x32_bf16(af[mt][ks], bfr, acc[mt], 0, 0, 0);
      }
      float cs = 0.f;
#pragma unroll
      for (int mt = 0; mt < 4; ++mt)
#pragma unroll
        for (int r = 0; r < 4; ++r) cs = fmaf(creg[mt][r], fexp2(acc[mt][r]), cs);
      cs += __shfl_xor(cs, 16, 64);
      cs += __shfl_xor(cs, 32, 64);
      if (lane < 16)
        atomicAdd(&w[b * SS + j0 + jt * 128 + wave * 32 + nt * 16 + lane], cs);
    }
  }
}

// ---------------------------------------------------------------------------
// finalize: v[b,d] = sum_j w[b,j] * x[b,j,d].  grid 512 (64 j per block).
// ---------------------------------------------------------------------------
__global__ __launch_bounds__(256) void finalize(
    const float* __restrict__ x, const float* __restrict__ w,
    float* __restrict__ out) {
  const int b = blockIdx.x >> 5;
  const int j0 = (blockIdx.x & 31) * 64;
  const int tid = threadIdx.x;
  const int d = tid & 127, jo = tid >> 7;
  float acc = 0.f;
  for (int jj = 0; jj < 32; ++jj) {
    int j = j0 + jj * 2 + jo;
    acc = fmaf(w[b * SS + j], x[((size_t)b * SS + j) * DD + d], acc);
  }
  __shared__ float red[256];
  red[tid] = acc;
  __syncthreads();
  if (tid < 128) atomicAdd(&out[b * DD + tid], red[tid] + red[tid + 128]);
}

extern "C" void kernel_launch(void* const* d_in, const int* in_sizes, int n_in,
                              void* d_out, int out_size, void* d_ws, size_t ws_size,
                              hipStream_t stream) {
  const float* x = (const float*)d_in[0];
  const float* t = (const float*)d_in[1];
  const float* Wq = (const float*)d_in[2];
  const float* Wk = (const float*)d_in[3];
  const float* theta = (const float*)d_in[4];
  const float* mu = (const float*)d_in[5];
  float* out = (float*)d_out;

  ushort_t* qb = (ushort_t*)d_ws;                       // 8.4 MB
  ushort_t* kb = qb + (size_t)BB * SS * DD;             // 8.4 MB
  ushort_t* wt_g = kb + (size_t)BB * SS * DD;           // 64 KB
  float* l = (float*)(wt_g + 256 * 128);                // 128 KB
  float* c = l + (size_t)BB * SS;                       // 128 KB
  float* w = c + (size_t)BB * SS;                       // 128 KB

  hipMemsetAsync(l, 0, (size_t)BB * SS * sizeof(float), stream);
  hipMemsetAsync(w, 0, (size_t)BB * SS * sizeof(float), stream);
  hipMemsetAsync(d_out, 0, (size_t)BB * DD * sizeof(float), stream);

  wprep<<<dim3(128), dim3(256), 0, stream>>>(Wq, Wk, wt_g);
  qk_gemm<<<dim3(512), dim3(256), 0, stream>>>(x, wt_g, qb, kb);
  rowsum<<<dim3(2048), dim3(256), 0, stream>>>(qb, kb, l);
  cvec<<<dim3(128), dim3(256), 0, stream>>>(t, theta, mu, l, c);
  colsum<<<dim3(2048), dim3(256), 0, stream>>>(qb, kb, c, w);
  finalize<<<dim3(512), dim3(256), 0, stream>>>(x, w, out);
}

// Round 4
// 127.277 us; speedup vs baseline: 1.3569x; 1.3569x over previous
//
#include <hip/hip_runtime.h>
#include <hip/hip_bf16.h>

#define SS 2048
#define DD 128
#define BB 16
#define LDST 136  // xs staging pad (ushorts)
#define SCT 268   // sc stride: 4-way max on frag-order epilogue reads

typedef short bf16x8 __attribute__((ext_vector_type(8)));
typedef float f32x4 __attribute__((ext_vector_type(4)));
typedef unsigned short ushort_t;

__device__ __forceinline__ unsigned short f2bf(float f) {
  union { float f; unsigned u; } v; v.f = f;
  unsigned r = v.u + 0x7fffu + ((v.u >> 16) & 1u);  // RNE
  return (unsigned short)(r >> 16);
}
__device__ __forceinline__ float fexp2(float x) { return __builtin_amdgcn_exp2f(x); }

// Fragment-major layout: chunk index ((G*4 + ks)*64 + lane), 16 B each.
// G = global 16-row group (b*128 + g), lane = quad*16 + lq holds
// rows[G*16+lq], cols[ks*32+quad*8 .. +8]. A and B frag loads are then
// one coalesced dwordx4 per (G,ks): lane L reads chunk base + L*16.

// ---------------------------------------------------------------------------
// wprep: wt_g = [Wq^T * log2e/sqrt(U) ; Wk^T] bf16 [256][128]. grid 128.
// ---------------------------------------------------------------------------
__global__ __launch_bounds__(256) void wprep(
    const float* __restrict__ Wq, const float* __restrict__ Wk,
    ushort_t* __restrict__ wt_g) {
  int idx = blockIdx.x * 256 + threadIdx.x;  // 0..32767
  int r = idx & 16383, uu = r >> 7, d = r & 127;
  if (idx < 16384)
    wt_g[uu * 128 + d] = f2bf(Wq[d * 128 + uu] * 0.1275174346f);  // log2e/sqrt(128)
  else
    wt_g[(uu + 128) * 128 + d] = f2bf(Wk[d * 128 + uu]);
}

// ---------------------------------------------------------------------------
// qk_gemm: [q|k] = bf16(x) @ wt_g^T, output in FRAG-MAJOR layout.
// grid 512 (64 rows/block), block 256.
// ---------------------------------------------------------------------------
__global__ __launch_bounds__(256, 2) void qk_gemm(
    const float* __restrict__ x, const ushort_t* __restrict__ wt_g,
    uint4* __restrict__ qF, uint4* __restrict__ kF) {
  __shared__ ushort_t xs[64 * LDST];
  __shared__ ushort_t sc[64 * SCT];
  const int tid = threadIdx.x, wave = tid >> 6, lane = tid & 63;
  const int lq = lane & 15, quad = lane >> 4;
  const int m0 = blockIdx.x * 64;

#pragma unroll
  for (int i = 0; i < 8; ++i) {  // stage x: 64x128 fp32 -> bf16
    int idx = i * 256 + tid;
    int row = idx >> 5, c4 = (idx & 31) * 4;
    const float4 v = *(const float4*)(x + (size_t)(m0 + row) * DD + c4);
    ushort4 h;
    h.x = f2bf(v.x); h.y = f2bf(v.y); h.z = f2bf(v.z); h.w = f2bf(v.w);
    *(ushort4*)(&xs[row * LDST + c4]) = h;
  }
  bf16x8 wf[4][4];  // wave's 64 output cols, K=128
#pragma unroll
  for (int nt = 0; nt < 4; ++nt)
#pragma unroll
    for (int ks = 0; ks < 4; ++ks)
      wf[nt][ks] = *(const bf16x8*)(wt_g + (wave * 64 + nt * 16 + lq) * 128 + ks * 32 + quad * 8);
  __syncthreads();

  f32x4 acc[4][4];
#pragma unroll
  for (int mt = 0; mt < 4; ++mt)
#pragma unroll
    for (int nt = 0; nt < 4; ++nt) acc[mt][nt] = (f32x4){0.f, 0.f, 0.f, 0.f};
#pragma unroll
  for (int mt = 0; mt < 4; ++mt) {
    bf16x8 af[4];
#pragma unroll
    for (int ks = 0; ks < 4; ++ks)
      af[ks] = *(const bf16x8*)(&xs[(mt * 16 + lq) * LDST + ks * 32 + quad * 8]);
#pragma unroll
    for (int nt = 0; nt < 4; ++nt)
#pragma unroll
      for (int ks = 0; ks < 4; ++ks)
        acc[mt][nt] = __builtin_amdgcn_mfma_f32_16x16x32_bf16(af[ks], wf[nt][ks], acc[mt][nt], 0, 0, 0);
  }
  // C/D: row = mt*16+quad*4+r, col = wave*64+nt*16+lq
#pragma unroll
  for (int mt = 0; mt < 4; ++mt)
#pragma unroll
    for (int nt = 0; nt < 4; ++nt)
#pragma unroll
      for (int r = 0; r < 4; ++r)
        sc[(mt * 16 + quad * 4 + r) * SCT + wave * 64 + nt * 16 + lq] = f2bf(acc[mt][nt][r]);
  __syncthreads();
  // epilogue: re-read in fragment order, store coalesced frag-major chunks
#pragma unroll
  for (int i = 0; i < 8; ++i) {
    int c = i * 256 + tid;                 // 0..2047
    int lane_c = c & 63, ks_c = (c >> 6) & 3, g_c = (c >> 8) & 3, isk = c >> 10;
    int li = lane_c & 15, qd = lane_c >> 4;
    int col = isk * 128 + ks_c * 32 + qd * 8;
    uint4 v = *(const uint4*)(&sc[(g_c * 16 + li) * SCT + col]);
    size_t G = (size_t)blockIdx.x * 4 + g_c;
    uint4* dst = isk ? kF : qF;
    dst[(G * 4 + ks_c) * 64 + lane_c] = v;
  }
}

// ---------------------------------------------------------------------------
// attn_fused: both softmax passes, NO LDS in K-loop, frag-major direct
// coalesced loads, manual ping-pong prefetch.  grid 512 = b(16) x ib(32),
// block 256 (4 waves); wave w owns j-groups {jt*8+2w, jt*8+2w+1}.
// ---------------------------------------------------------------------------
__global__ __launch_bounds__(256, 2) void attn_fused(
    const uint4* __restrict__ qF, const uint4* __restrict__ kF,
    const float* __restrict__ t, const float* __restrict__ theta,
    const float* __restrict__ mu, float* __restrict__ w) {
  const int b = blockIdx.x >> 5;
  const int ib = blockIdx.x & 31;
  const int i0 = ib * 64;
  const int tid = threadIdx.x, wave = tid >> 6, lane = tid & 63;
  const int lq = lane & 15, quad = lane >> 4;

  __shared__ float rs_lds[4][64];
  __shared__ float c_lds[64];

  const bf16x8* qc = (const bf16x8*)qF;
  const bf16x8* kc = (const bf16x8*)kF;

  // A frags: 64 q-rows x K=128, one coalesced dwordx4 per (mt,ks)
  bf16x8 af[4][4];
#pragma unroll
  for (int mt = 0; mt < 4; ++mt)
#pragma unroll
    for (int ks = 0; ks < 4; ++ks)
      af[mt][ks] = qc[((size_t)(b * 128 + ib * 4 + mt) * 4 + ks) * 64 + lane];

  bf16x8 cur[2][4], nxt[2][4];
  auto load_tile = [&](bf16x8 (&f)[2][4], int jt) {
#pragma unroll
    for (int nt = 0; nt < 2; ++nt) {
      int gg = jt * 8 + wave * 2 + nt;
#pragma unroll
      for (int ks = 0; ks < 4; ++ks)
        f[nt][ks] = kc[((size_t)(b * 128 + gg) * 4 + ks) * 64 + lane];
    }
  };

  float rowsum[4][4];
#pragma unroll
  for (int mt = 0; mt < 4; ++mt)
#pragma unroll
    for (int r = 0; r < 4; ++r) rowsum[mt][r] = 0.f;

  auto compute_p1 = [&](bf16x8 (&f)[2][4]) {
#pragma unroll
    for (int nt = 0; nt < 2; ++nt) {
      f32x4 acc[4];
#pragma unroll
      for (int mt = 0; mt < 4; ++mt) acc[mt] = (f32x4){0.f, 0.f, 0.f, 0.f};
#pragma unroll
      for (int ks = 0; ks < 4; ++ks)
#pragma unroll
        for (int mt = 0; mt < 4; ++mt)
          acc[mt] = __builtin_amdgcn_mfma_f32_16x16x32_bf16(af[mt][ks], f[nt][ks], acc[mt], 0, 0, 0);
#pragma unroll
      for (int mt = 0; mt < 4; ++mt)
#pragma unroll
        for (int r = 0; r < 4; ++r) rowsum[mt][r] += fexp2(acc[mt][r]);
    }
  };

  // ---- PASS 1: row sums ----
  load_tile(cur, 0);
  for (int jt = 0; jt < 16; jt += 2) {
    load_tile(nxt, jt + 1);
    compute_p1(cur);
    if (jt + 2 < 16) load_tile(cur, jt + 2);
    compute_p1(nxt);
  }

#pragma unroll
  for (int d2 = 1; d2 <= 8; d2 <<= 1)
#pragma unroll
    for (int mt = 0; mt < 4; ++mt)
#pragma unroll
      for (int r = 0; r < 4; ++r)
        rowsum[mt][r] += __shfl_xor(rowsum[mt][r], d2, 64);
  if (lq == 0) {
#pragma unroll
    for (int mt = 0; mt < 4; ++mt)
#pragma unroll
      for (int r = 0; r < 4; ++r)
        rs_lds[wave][mt * 16 + quad * 4 + r] = rowsum[mt][r];
  }
  __syncthreads();
  if (tid < 64) {
    float l = rs_lds[0][tid] + rs_lds[1][tid] + rs_lds[2][tid] + rs_lds[3][tid];
    int gi = i0 + tid;
    float z = theta[gi] - mu[gi] * t[b * SS + gi];
    float tf = 1.f / (1.f + fexp2(-z * 1.44269504f));
    c_lds[tid] = tf / l;
  }
  __syncthreads();
  float creg[4][4];
#pragma unroll
  for (int mt = 0; mt < 4; ++mt)
#pragma unroll
    for (int r = 0; r < 4; ++r) creg[mt][r] = c_lds[mt * 16 + quad * 4 + r];

  auto compute_p2 = [&](bf16x8 (&f)[2][4], int jt) {
#pragma unroll
    for (int nt = 0; nt < 2; ++nt) {
      f32x4 acc[4];
#pragma unroll
      for (int mt = 0; mt < 4; ++mt) acc[mt] = (f32x4){0.f, 0.f, 0.f, 0.f};
#pragma unroll
      for (int ks = 0; ks < 4; ++ks)
#pragma unroll
        for (int mt = 0; mt < 4; ++mt)
          acc[mt] = __builtin_amdgcn_mfma_f32_16x16x32_bf16(af[mt][ks], f[nt][ks], acc[mt], 0, 0, 0);
      float cs = 0.f;
#pragma unroll
      for (int mt = 0; mt < 4; ++mt)
#pragma unroll
        for (int r = 0; r < 4; ++r) cs = fmaf(creg[mt][r], fexp2(acc[mt][r]), cs);
      cs += __shfl_xor(cs, 16, 64);
      cs += __shfl_xor(cs, 32, 64);
      if (lane < 16)
        atomicAdd(&w[b * SS + (jt * 8 + wave * 2 + nt) * 16 + lane], cs);
    }
  };

  // ---- PASS 2: column sums -> w ----
  load_tile(cur, 0);
  for (int jt = 0; jt < 16; jt += 2) {
    load_tile(nxt, jt + 1);
    compute_p2(cur, jt);
    if (jt + 2 < 16) load_tile(cur, jt + 2);
    compute_p2(nxt, jt + 1);
  }
}

// ---------------------------------------------------------------------------
// finalize: v[b,d] = sum_j w[b,j] * x[b,j,d].  grid 512 (64 j per block).
// ---------------------------------------------------------------------------
__global__ __launch_bounds__(256) void finalize(
    const float* __restrict__ x, const float* __restrict__ w,
    float* __restrict__ out) {
  const int b = blockIdx.x >> 5;
  const int j0 = (blockIdx.x & 31) * 64;
  const int tid = threadIdx.x;
  const int d = tid & 127, jo = tid >> 7;
  float acc = 0.f;
  for (int jj = 0; jj < 32; ++jj) {
    int j = j0 + jj * 2 + jo;
    acc = fmaf(w[b * SS + j], x[((size_t)b * SS + j) * DD + d], acc);
  }
  __shared__ float red[256];
  red[tid] = acc;
  __syncthreads();
  if (tid < 128) atomicAdd(&out[b * DD + tid], red[tid] + red[tid + 128]);
}

extern "C" void kernel_launch(void* const* d_in, const int* in_sizes, int n_in,
                              void* d_out, int out_size, void* d_ws, size_t ws_size,
                              hipStream_t stream) {
  const float* x = (const float*)d_in[0];
  const float* t = (const float*)d_in[1];
  const float* Wq = (const float*)d_in[2];
  const float* Wk = (const float*)d_in[3];
  const float* theta = (const float*)d_in[4];
  const float* mu = (const float*)d_in[5];
  float* out = (float*)d_out;

  uint4* qF = (uint4*)d_ws;                             // 8.4 MB (frag-major)
  uint4* kF = qF + (size_t)2048 * 4 * 64;               // 8.4 MB (frag-major)
  ushort_t* wt_g = (ushort_t*)(kF + (size_t)2048 * 4 * 64);  // 64 KB
  float* w = (float*)(wt_g + 256 * 128);                // 128 KB

  hipMemsetAsync(w, 0, (size_t)BB * SS * sizeof(float), stream);
  hipMemsetAsync(d_out, 0, (size_t)BB * DD * sizeof(float), stream);

  wprep<<<dim3(128), dim3(256), 0, stream>>>(Wq, Wk, wt_g);
  qk_gemm<<<dim3(512), dim3(256), 0, stream>>>(x, wt_g, qF, kF);
  attn_fused<<<dim3(512), dim3(256), 0, stream>>>(qF, kF, t, theta, mu, w);
  finalize<<<dim3(512), dim3(256), 0, stream>>>(x, w, out);
}